// Round 1
// baseline (7998.870 us; speedup 1.0000x reference)
//
#include <hip/hip_runtime.h>
#include <math.h>

#define NROWS 32768
#define DIM 1024
#define NGLOB 1024
#define NLOC 256
#define NCOMB 1280
#define MOM_G 0.999f
#define MOM_L 0.8f
#define TEMP_INV (1.0f / 0.07f)
#define EPSN 1e-12f

// ---------------- block reduce helpers (256 threads = 4 waves) ----------------
__device__ __forceinline__ float block_sum(float v, float* sbuf) {
#pragma unroll
    for (int off = 32; off > 0; off >>= 1) v += __shfl_down(v, off, 64);
    int lane = threadIdx.x & 63, wid = threadIdx.x >> 6;
    if (lane == 0) sbuf[wid] = v;
    __syncthreads();
    if (threadIdx.x == 0) sbuf[0] = sbuf[0] + sbuf[1] + sbuf[2] + sbuf[3];
    __syncthreads();
    float r = sbuf[0];
    __syncthreads();
    return r;
}

__device__ __forceinline__ float block_max(float v, float* sbuf) {
#pragma unroll
    for (int off = 32; off > 0; off >>= 1) v = fmaxf(v, __shfl_down(v, off, 64));
    int lane = threadIdx.x & 63, wid = threadIdx.x >> 6;
    if (lane == 0) sbuf[wid] = v;
    __syncthreads();
    if (threadIdx.x == 0) sbuf[0] = fmaxf(fmaxf(sbuf[0], sbuf[1]), fmaxf(sbuf[2], sbuf[3]));
    __syncthreads();
    float r = sbuf[0];
    __syncthreads();
    return r;
}

// ---------------- fp32 tiled GEMM: 128x128 tile, BK=8, 256 thr, 8x8/thread ----
// OP: 0=none, 1=bias+relu, 2=bias, 3=bias+sigmoid, 4=clean (C = Z - G*acc)
// BT=false: B is [K,Ncols] row-major (A@B). BT=true: B is [Ncols,K] (A@B^T).
// A loads are scalar (A may be 4B-misaligned: z_proj output slot).
template <int OP, bool BT>
__global__ __launch_bounds__(256) void k_gemm(
    const float* __restrict__ A, const float* __restrict__ B,
    float* __restrict__ C, int M, int Ncols, int K,
    const float* __restrict__ bias, const float* __restrict__ Zf,
    const float* __restrict__ Gt)
{
    __shared__ float As[8][128];
    __shared__ float Bs[8][128];
    const int tid = threadIdx.x;
    const int m0 = blockIdx.y * 128;
    const int n0 = blockIdx.x * 128;
    const int ty = tid >> 4, tx = tid & 15;
    float acc[8][8] = {};
    const int arow = tid >> 1;
    const int ak = (tid & 1) * 4;
    const float* aptr = A + (size_t)(m0 + arow) * K + ak;

    for (int k0 = 0; k0 < K; k0 += 8) {
        float a0 = aptr[k0], a1 = aptr[k0 + 1], a2 = aptr[k0 + 2], a3 = aptr[k0 + 3];
        As[ak][arow] = a0; As[ak + 1][arow] = a1; As[ak + 2][arow] = a2; As[ak + 3][arow] = a3;
        if (BT) {
            const float* bp = B + (size_t)(n0 + arow) * K + k0 + ak;
            float b0 = bp[0], b1 = bp[1], b2 = bp[2], b3 = bp[3];
            Bs[ak][arow] = b0; Bs[ak + 1][arow] = b1; Bs[ak + 2][arow] = b2; Bs[ak + 3][arow] = b3;
        } else {
            const int brow = tid >> 5, bcol = (tid & 31) * 4;
            float4 bv = *(const float4*)(B + (size_t)(k0 + brow) * Ncols + n0 + bcol);
            *(float4*)(&Bs[brow][bcol]) = bv;
        }
        __syncthreads();
#pragma unroll
        for (int kk = 0; kk < 8; ++kk) {
            float a[8], b[8];
            *(float4*)&a[0] = *(const float4*)&As[kk][ty * 8];
            *(float4*)&a[4] = *(const float4*)&As[kk][ty * 8 + 4];
            *(float4*)&b[0] = *(const float4*)&Bs[kk][tx * 8];
            *(float4*)&b[4] = *(const float4*)&Bs[kk][tx * 8 + 4];
#pragma unroll
            for (int j = 0; j < 8; ++j)
#pragma unroll
                for (int i = 0; i < 8; ++i)
                    acc[j][i] = fmaf(a[j], b[i], acc[j][i]);
        }
        __syncthreads();
    }
#pragma unroll
    for (int j = 0; j < 8; ++j) {
        int row = m0 + ty * 8 + j;
        size_t rbase = (size_t)row * Ncols + n0 + tx * 8;
#pragma unroll
        for (int i = 0; i < 8; ++i) {
            float v = acc[j][i];
            int col = n0 + tx * 8 + i;
            if (OP == 1) v = fmaxf(v + bias[col], 0.0f);
            else if (OP == 2) v = v + bias[col];
            else if (OP == 3) v = 1.0f / (1.0f + __expf(-(v + bias[col])));
            else if (OP == 4) v = Zf[rbase + i] - Gt[rbase + i] * v;
            C[rbase + i] = v;  // scalar stores: C may be 4B-misaligned (z_proj slot)
        }
    }
}

// ---------------- rowwise l2-normalize (one block / row), optional raw copy ---
__global__ __launch_bounds__(256) void k_rownorm(
    const float* __restrict__ in, float* __restrict__ outn, float* __restrict__ copy_out)
{
    __shared__ float sbuf[4];
    const int r = blockIdx.x, t = threadIdx.x;
    const float* row = in + (size_t)r * DIM + t * 4;
    float v0 = row[0], v1 = row[1], v2 = row[2], v3 = row[3];
    float ss = block_sum(v0 * v0 + v1 * v1 + v2 * v2 + v3 * v3, sbuf);
    float inv = 1.0f / fmaxf(sqrtf(ss), EPSN);
    float* o = outn + (size_t)r * DIM + t * 4;
    o[0] = v0 * inv; o[1] = v1 * inv; o[2] = v2 * inv; o[3] = v3 * inv;
    if (copy_out) {
        float* c = copy_out + (size_t)r * DIM + t * 4;
        c[0] = v0; c[1] = v1; c[2] = v2; c[3] = v3;
    }
}

// ---------------- concat old dicts into comb_old [NCOMB, DIM] -----------------
__global__ __launch_bounds__(256) void k_copy2(
    const float* __restrict__ a, const float* __restrict__ b, float* __restrict__ dst)
{
    int i = blockIdx.x * 256 + threadIdx.x;
    const int na = NGLOB * DIM;
    dst[i] = (i < na) ? a[i] : b[i - na];
}

// ---------------- per-row argmax over S0 segments + histogram -----------------
__global__ __launch_bounds__(256) void k_argmax(
    const float* __restrict__ S0, int* __restrict__ idx_g, int* __restrict__ idx_l,
    int* __restrict__ cnt_g, int* __restrict__ cnt_l)
{
    __shared__ float sv[256];
    __shared__ int si[256];
    const int r = blockIdx.x, t = threadIdx.x;
    const float* row = S0 + (size_t)r * NCOMB;

    float best = -3.0e38f; int bi = 0;
    for (int c = t; c < NGLOB; c += 256) {
        float v = row[c];
        if (v > best) { best = v; bi = c; }   // ascending c: keeps first max
    }
    sv[t] = best; si[t] = bi;
    __syncthreads();
    for (int s = 128; s > 0; s >>= 1) {
        if (t < s) {
            if (sv[t + s] > sv[t] || (sv[t + s] == sv[t] && si[t + s] < si[t])) {
                sv[t] = sv[t + s]; si[t] = si[t + s];
            }
        }
        __syncthreads();
    }
    if (t == 0) { idx_g[r] = si[0]; atomicAdd(&cnt_g[si[0]], 1); }
    __syncthreads();

    float v = row[NGLOB + t];
    sv[t] = v; si[t] = t;
    __syncthreads();
    for (int s = 128; s > 0; s >>= 1) {
        if (t < s) {
            if (sv[t + s] > sv[t] || (sv[t + s] == sv[t] && si[t + s] < si[t])) {
                sv[t] = sv[t + s]; si[t] = si[t + s];
            }
        }
        __syncthreads();
    }
    if (t == 0) { idx_l[r] = si[0]; atomicAdd(&cnt_l[si[0]], 1); }
}

// ---------------- tiny serial exclusive scan (1280 entries) -------------------
__global__ void k_scan(const int* __restrict__ cg, const int* __restrict__ cl,
                       int* __restrict__ bg, int* __restrict__ bl)
{
    if (threadIdx.x == 0 && blockIdx.x == 0) {
        int s = 0;
        for (int i = 0; i < NGLOB; ++i) { bg[i] = s; s += cg[i]; }
        s = 0;
        for (int i = 0; i < NLOC; ++i) { bl[i] = s; s += cl[i]; }
    }
}

// ---------------- scatter row ids into per-code lists -------------------------
__global__ __launch_bounds__(256) void k_scatter(
    const int* __restrict__ idx_g, const int* __restrict__ idx_l,
    const int* __restrict__ base_g, const int* __restrict__ base_l,
    int* __restrict__ cur_g, int* __restrict__ cur_l,
    int* __restrict__ rl_g, int* __restrict__ rl_l)
{
    int n = blockIdx.x * 256 + threadIdx.x;
    int ig = idx_g[n];
    int p = atomicAdd(&cur_g[ig], 1);
    rl_g[base_g[ig] + p] = n;
    int il = idx_l[n];
    p = atomicAdd(&cur_l[il], 1);
    rl_l[base_l[il] + p] = n;
}

// ---------------- EMA dict update + l2norm, one block per code ----------------
__global__ __launch_bounds__(256) void k_dict_update(
    const float* __restrict__ nn, const float* __restrict__ gdict, const float* __restrict__ ldict,
    const int* __restrict__ cnt_g, const int* __restrict__ cnt_l,
    const int* __restrict__ base_g, const int* __restrict__ base_l,
    const int* __restrict__ rl_g, const int* __restrict__ rl_l,
    float* __restrict__ comb)
{
    __shared__ float sbuf[4];
    const int k = blockIdx.x, t = threadIdx.x;
    const float* drow;
    const int* list;
    int cnt; float m;
    if (k < NGLOB) { drow = gdict + (size_t)k * DIM; cnt = cnt_g[k]; list = rl_g + base_g[k]; m = MOM_G; }
    else { int kl = k - NGLOB; drow = ldict + (size_t)kl * DIM; cnt = cnt_l[kl]; list = rl_l + base_l[kl]; m = MOM_L; }
    const int d0 = t * 4;
    float a0 = 0, a1 = 0, a2 = 0, a3 = 0;
    for (int i = 0; i < cnt; ++i) {
        const float* rp = nn + (size_t)list[i] * DIM + d0;
        a0 += rp[0]; a1 += rp[1]; a2 += rp[2]; a3 += rp[3];
    }
    float u0 = drow[d0], u1 = drow[d0 + 1], u2 = drow[d0 + 2], u3 = drow[d0 + 3];
    if (cnt > 0) {
        float ic = (1.0f - m) / (float)cnt;
        u0 = m * u0 + a0 * ic; u1 = m * u1 + a1 * ic;
        u2 = m * u2 + a2 * ic; u3 = m * u3 + a3 * ic;
    }
    float ss = block_sum(u0 * u0 + u1 * u1 + u2 * u2 + u3 * u3, sbuf);
    float inv = 1.0f / fmaxf(sqrtf(ss), EPSN);
    float* o = comb + (size_t)k * DIM + d0;
    o[0] = u0 * inv; o[1] = u1 * inv; o[2] = u2 * inv; o[3] = u3 * inv;
}

// ---------------- softmax over NCOMB (in place) + abs-sum losses --------------
__global__ __launch_bounds__(256) void k_softmax_loss(float* __restrict__ S, float* __restrict__ accum)
{
    __shared__ float sbuf[4];
    const int r = blockIdx.x, t = threadIdx.x;
    float* row = S + (size_t)r * NCOMB;
    float v[5];
    float mx = -3.0e38f, ag = 0.0f, al = 0.0f;
#pragma unroll
    for (int j = 0; j < 5; ++j) {
        v[j] = row[t + j * 256];
        mx = fmaxf(mx, v[j]);
        float a = fabsf(v[j]);
        if (j < 4) ag += a; else al += a;   // cols [0,1024) vs [1024,1280)
    }
    mx = block_max(mx, sbuf);
    ag = block_sum(ag, sbuf);
    al = block_sum(al, sbuf);
    float e[5], es = 0.0f;
#pragma unroll
    for (int j = 0; j < 5; ++j) { e[j] = __expf((v[j] - mx) * TEMP_INV); es += e[j]; }
    es = block_sum(es, sbuf);
    float inv = 1.0f / es;
#pragma unroll
    for (int j = 0; j < 5; ++j) row[t + j * 256] = e[j] * inv;
    if (t == 0) { atomicAdd(&accum[0], ag); atomicAdd(&accum[1], al); }
}

// ---------------- |row dot| for loss_direct -----------------------------------
__global__ __launch_bounds__(256) void k_loss_direct(
    const float* __restrict__ zn, const float* __restrict__ un, float* __restrict__ accum)
{
    __shared__ float sbuf[4];
    const int r = blockIdx.x, t = threadIdx.x;
    const float* a = zn + (size_t)r * DIM + t * 4;
    const float* b = un + (size_t)r * DIM + t * 4;
    float d = a[0] * b[0] + a[1] * b[1] + a[2] * b[2] + a[3] * b[3];
    d = block_sum(d, sbuf);
    if (t == 0) atomicAdd(&accum[2], fabsf(d));
}

__global__ void k_loss_final(const float* __restrict__ accum, float* __restrict__ out_loss)
{
    if (threadIdx.x == 0 && blockIdx.x == 0)
        out_loss[0] = accum[0] / ((float)NROWS * (float)NGLOB)
                    + accum[1] / ((float)NROWS * (float)NLOC)
                    + accum[2] / (float)NROWS;
}

// ------------------------------------------------------------------------------
extern "C" void kernel_launch(void* const* d_in, const int* in_sizes, int n_in,
                              void* d_out, int out_size, void* d_ws, size_t ws_size,
                              hipStream_t stream)
{
    (void)in_sizes; (void)n_in; (void)out_size; (void)ws_size;
    const float* z_flat = (const float*)d_in[0];
    const float* u_flat = (const float*)d_in[1];
    const float* W1 = (const float*)d_in[2];
    const float* b1 = (const float*)d_in[3];
    const float* W2 = (const float*)d_in[4];
    const float* b2 = (const float*)d_in[5];
    const float* Wg = (const float*)d_in[6];
    const float* bg = (const float*)d_in[7];
    const float* gdict = (const float*)d_in[8];
    const float* ldict = (const float*)d_in[9];

    const size_t ND = (size_t)NROWS * DIM;
    float* out = (float*)d_out;
    float* out_zclean = out;            // [N,D]
    float* out_loss = out + ND;         // scalar
    float* out_zproj = out + ND + 1;    // [N,D]  (4B-misaligned base!)
    float* out_u = out + 2 * ND + 1;    // [N,D]  (4B-misaligned base!)

    float* wsf = (float*)d_ws;
    float* noise_norm = wsf;                              // ND
    float* hbuf = noise_norm + ND;                        // ND (h -> z_norm -> gate)
    float* S = hbuf + ND;                                 // N*NCOMB
    float* comb_old = S + (size_t)NROWS * NCOMB;          // NCOMB*DIM
    float* comb_new = comb_old + (size_t)NCOMB * DIM;     // NCOMB*DIM
    int* cnt_g = (int*)(comb_new + (size_t)NCOMB * DIM);  // 1024
    int* cnt_l = cnt_g + NGLOB;                           // 256
    int* cur_g = cnt_l + NLOC;                            // 1024
    int* cur_l = cur_g + NGLOB;                           // 256
    float* accum = (float*)(cur_l + NLOC);                // 4
    int* base_g = (int*)(accum + 4);                      // 1024
    int* base_l = base_g + NGLOB;                         // 256
    int* idx_g = base_l + NLOC;                           // N
    int* idx_l = idx_g + NROWS;                           // N
    int* rl_g = idx_l + NROWS;                            // N
    int* rl_l = rl_g + NROWS;                             // N

    // zero counts + cursors + loss accumulators (contiguous)
    size_t zero_bytes = (size_t)(NGLOB + NLOC + NGLOB + NLOC + 4) * sizeof(int);
    hipMemsetAsync(cnt_g, 0, zero_bytes, stream);

    dim3 blk(256);

    k_copy2<<<dim3(NCOMB * DIM / 256), blk, 0, stream>>>(gdict, ldict, comb_old);
    k_rownorm<<<dim3(NROWS), blk, 0, stream>>>(u_flat, noise_norm, out_u);

    // S0 = noise_norm @ comb_old^T   [N, NCOMB]
    k_gemm<0, true><<<dim3(NCOMB / 128, NROWS / 128), blk, 0, stream>>>(
        noise_norm, comb_old, S, NROWS, NCOMB, DIM, nullptr, nullptr, nullptr);

    k_argmax<<<dim3(NROWS), blk, 0, stream>>>(S, idx_g, idx_l, cnt_g, cnt_l);
    k_scan<<<dim3(1), dim3(64), 0, stream>>>(cnt_g, cnt_l, base_g, base_l);
    k_scatter<<<dim3(NROWS / 256), blk, 0, stream>>>(idx_g, idx_l, base_g, base_l,
                                                     cur_g, cur_l, rl_g, rl_l);
    k_dict_update<<<dim3(NCOMB), blk, 0, stream>>>(noise_norm, gdict, ldict,
                                                   cnt_g, cnt_l, base_g, base_l,
                                                   rl_g, rl_l, comb_new);

    // projector: h = relu(z@W1+b1); z_proj = h@W2+b2
    k_gemm<1, false><<<dim3(DIM / 128, NROWS / 128), blk, 0, stream>>>(
        z_flat, W1, hbuf, NROWS, DIM, DIM, b1, nullptr, nullptr);
    k_gemm<2, false><<<dim3(DIM / 128, NROWS / 128), blk, 0, stream>>>(
        hbuf, W2, out_zproj, NROWS, DIM, DIM, b2, nullptr, nullptr);

    // z_norm into hbuf (h no longer needed)
    k_rownorm<<<dim3(NROWS), blk, 0, stream>>>(out_zproj, hbuf, nullptr);

    // S1 = z_norm @ comb_new^T  (losses + softmax logits share this)
    k_gemm<0, true><<<dim3(NCOMB / 128, NROWS / 128), blk, 0, stream>>>(
        hbuf, comb_new, S, NROWS, NCOMB, DIM, nullptr, nullptr, nullptr);

    k_softmax_loss<<<dim3(NROWS), blk, 0, stream>>>(S, accum);
    k_loss_direct<<<dim3(NROWS), blk, 0, stream>>>(hbuf, noise_norm, accum);

    // gate = sigmoid(z_proj@Wg+bg) into hbuf (z_norm no longer needed)
    k_gemm<3, false><<<dim3(DIM / 128, NROWS / 128), blk, 0, stream>>>(
        out_zproj, Wg, hbuf, NROWS, DIM, DIM, bg, nullptr, nullptr);

    // z_clean = z_flat - gate * (weights @ comb_new)
    k_gemm<4, false><<<dim3(DIM / 128, NROWS / 128), blk, 0, stream>>>(
        S, comb_new, out_zclean, NROWS, DIM, NCOMB, nullptr, z_flat, hbuf);

    k_loss_final<<<dim3(1), dim3(64), 0, stream>>>(accum, out_loss);
}

// Round 2
// 2937.906 us; speedup vs baseline: 2.7226x; 2.7226x over previous
//
#include <hip/hip_runtime.h>
#include <math.h>

#define NROWS 32768
#define DIM 1024
#define NGLOB 1024
#define NLOC 256
#define NCOMB 1280
#define MOM_G 0.999f
#define MOM_L 0.8f
#define TEMP_INV (1.0f / 0.07f)
#define EPSN 1e-12f

typedef __bf16 bf16x8 __attribute__((ext_vector_type(8)));
typedef __bf16 bf16x4 __attribute__((ext_vector_type(4)));
typedef float f32x4 __attribute__((ext_vector_type(4)));

// async global->LDS, 16B per lane; lds dest = wave-uniform base + lane*16
__device__ __forceinline__ void gl2lds16(const void* g, void* l) {
    __builtin_amdgcn_global_load_lds(
        (const __attribute__((address_space(1))) void*)g,
        (__attribute__((address_space(3))) void*)l, 16, 0, 0);
}

// ---------------- block reduce helpers (256 threads = 4 waves) ----------------
__device__ __forceinline__ float block_sum(float v, float* sbuf) {
#pragma unroll
    for (int off = 32; off > 0; off >>= 1) v += __shfl_down(v, off, 64);
    int lane = threadIdx.x & 63, wid = threadIdx.x >> 6;
    if (lane == 0) sbuf[wid] = v;
    __syncthreads();
    if (threadIdx.x == 0) sbuf[0] = sbuf[0] + sbuf[1] + sbuf[2] + sbuf[3];
    __syncthreads();
    float r = sbuf[0];
    __syncthreads();
    return r;
}

__device__ __forceinline__ float block_max(float v, float* sbuf) {
#pragma unroll
    for (int off = 32; off > 0; off >>= 1) v = fmaxf(v, __shfl_down(v, off, 64));
    int lane = threadIdx.x & 63, wid = threadIdx.x >> 6;
    if (lane == 0) sbuf[wid] = v;
    __syncthreads();
    if (threadIdx.x == 0) sbuf[0] = fmaxf(fmaxf(sbuf[0], sbuf[1]), fmaxf(sbuf[2], sbuf[3]));
    __syncthreads();
    float r = sbuf[0];
    __syncthreads();
    return r;
}

// ---------------- bf16 MFMA GEMM: C = A @ Brows^T, 128x128 tile, BK=32 -------
// A: [M, lda] bf16 (uses first K of each row). Brows: [N, K] bf16.
// OP: 0 -> Cf = acc (fp32)
//     1 -> Cb = bf16(relu(acc + bias))
//     2 -> Cf = acc + bias (scalar stores; Cf may be 4B-only-aligned), Cb = bf16(same)
//     3 -> Cf = sigmoid(acc + bias)
//     4 -> Cf = Zf - Gt * acc
template <int OP>
__global__ __launch_bounds__(256) void k_mgemm(
    const __bf16* __restrict__ A, const __bf16* __restrict__ Brows,
    int M, int N, int K, int lda,
    float* __restrict__ Cf, __bf16* __restrict__ Cb,
    const float* __restrict__ bias,
    const float* __restrict__ Zf, const float* __restrict__ Gt)
{
    __shared__ __bf16 As[128 * 32];
    __shared__ __bf16 Bs[128 * 32];
    const int tid = threadIdx.x;
    const int wave = tid >> 6;
    const int lane = tid & 63;
    const int col = lane & 15, quad = lane >> 4;
    const int m0 = blockIdx.y * 128, n0 = blockIdx.x * 128;
    const int wm = (wave >> 1) * 64, wn = (wave & 1) * 64;

    // staging: 8192B per tile; thread t owns 16B chunks t and t+256
    const int arow = tid >> 2;        // 0..63
    const int achk = (tid & 3) * 8;   // k-elem offset 0,8,16,24
    const __bf16* gA  = A + (size_t)(m0 + arow) * lda + achk;
    const __bf16* gA2 = A + (size_t)(m0 + 64 + arow) * lda + achk;
    const __bf16* gB  = Brows + (size_t)(n0 + arow) * K + achk;
    const __bf16* gB2 = Brows + (size_t)(n0 + 64 + arow) * K + achk;
    char* lA = (char*)As + wave * 1024;
    char* lB = (char*)Bs + wave * 1024;

    f32x4 acc[4][4] = {};

    for (int k0 = 0; k0 < K; k0 += 32) {
        __syncthreads();                  // all waves done reading previous tile
        gl2lds16(gA + k0, lA);
        gl2lds16(gA2 + k0, lA + 4096);
        gl2lds16(gB + k0, lB);
        gl2lds16(gB2 + k0, lB + 4096);
        __syncthreads();                  // compiler drains vmcnt(0) here

        bf16x8 af[4], bfv[4];
#pragma unroll
        for (int i = 0; i < 4; ++i) {
            af[i]  = *(const bf16x8*)(As + (wm + 16 * i + col) * 32 + quad * 8);
            bfv[i] = *(const bf16x8*)(Bs + (wn + 16 * i + col) * 32 + quad * 8);
        }
#pragma unroll
        for (int i = 0; i < 4; ++i)
#pragma unroll
            for (int j = 0; j < 4; ++j)
                acc[i][j] = __builtin_amdgcn_mfma_f32_16x16x32_bf16(
                    af[i], bfv[j], acc[i][j], 0, 0, 0);
    }

    // C/D layout: n = lane&15, m = quad*4 + reg  (within each 16x16 tile)
#pragma unroll
    for (int i = 0; i < 4; ++i) {
#pragma unroll
        for (int j = 0; j < 4; ++j) {
            int n = n0 + wn + 16 * j + col;
#pragma unroll
            for (int r = 0; r < 4; ++r) {
                int m = m0 + wm + 16 * i + quad * 4 + r;
                size_t idx = (size_t)m * N + n;
                float v = acc[i][j][r];
                if (OP == 1) {
                    v = fmaxf(v + bias[n], 0.0f);
                    Cb[idx] = (__bf16)v;
                } else if (OP == 2) {
                    v += bias[n];
                    Cf[idx] = v;           // scalar store (misaligned-base safe)
                    Cb[idx] = (__bf16)v;
                } else if (OP == 3) {
                    v = 1.0f / (1.0f + __expf(-(v + bias[n])));
                    Cf[idx] = v;
                } else if (OP == 4) {
                    v = Zf[idx] - Gt[idx] * v;
                    Cf[idx] = v;
                } else {
                    Cf[idx] = v;
                }
            }
        }
    }
}

// ---------------- fp32 -> bf16 elementwise convert (4/thread) -----------------
__global__ __launch_bounds__(256) void k_f2b(
    const float* __restrict__ in, __bf16* __restrict__ out)
{
    int i = blockIdx.x * 256 + threadIdx.x;
    float4 v = ((const float4*)in)[i];
    bf16x4 o = {(__bf16)v.x, (__bf16)v.y, (__bf16)v.z, (__bf16)v.w};
    ((bf16x4*)out)[i] = o;
}

// ---------------- rowwise l2norm: fp32 out / bf16 out / raw copy (nullable) ---
__global__ __launch_bounds__(256) void k_rownorm(
    const float* __restrict__ in, float* __restrict__ outf,
    __bf16* __restrict__ outb, float* __restrict__ copy_out)
{
    __shared__ float sbuf[4];
    const int r = blockIdx.x, t = threadIdx.x;
    const float* row = in + (size_t)r * DIM + t * 4;
    float v0 = row[0], v1 = row[1], v2 = row[2], v3 = row[3];
    float ss = block_sum(v0 * v0 + v1 * v1 + v2 * v2 + v3 * v3, sbuf);
    float inv = 1.0f / fmaxf(sqrtf(ss), EPSN);
    float n0 = v0 * inv, n1 = v1 * inv, n2 = v2 * inv, n3 = v3 * inv;
    size_t base = (size_t)r * DIM + t * 4;
    if (outf) { float* o = outf + base; o[0] = n0; o[1] = n1; o[2] = n2; o[3] = n3; }
    if (outb) {
        bf16x4 o = {(__bf16)n0, (__bf16)n1, (__bf16)n2, (__bf16)n3};
        *(bf16x4*)(outb + base) = o;
    }
    if (copy_out) { float* c = copy_out + base; c[0] = v0; c[1] = v1; c[2] = v2; c[3] = v3; }
}

// ---------------- concat old dicts -> comb_old bf16 [NCOMB, DIM] --------------
__global__ __launch_bounds__(256) void k_copy2(
    const float* __restrict__ a, const float* __restrict__ b, __bf16* __restrict__ dst)
{
    int i = blockIdx.x * 256 + threadIdx.x;
    const int na = NGLOB * DIM;
    float v = (i < na) ? a[i] : b[i - na];
    dst[i] = (__bf16)v;
}

// ---------------- transpose fp32 [dim,dim] -> bf16 [dim,dim]^T ----------------
__global__ __launch_bounds__(256) void k_tr_f2b(
    const float* __restrict__ in, __bf16* __restrict__ out, int dim)
{
    __shared__ __bf16 t[64][65];
    int r0 = blockIdx.y * 64, c0 = blockIdx.x * 64;
#pragma unroll
    for (int i = 0; i < 16; ++i) {
        int e = i * 256 + threadIdx.x;
        int r = e >> 6, c = e & 63;
        t[c][r] = (__bf16)in[(size_t)(r0 + r) * dim + c0 + c];
    }
    __syncthreads();
#pragma unroll
    for (int i = 0; i < 16; ++i) {
        int e = i * 256 + threadIdx.x;
        int r = e >> 6, c = e & 63;
        out[(size_t)(c0 + r) * dim + r0 + c] = t[r][c];
    }
}

// ---------------- transpose bf16 [R,C] -> bf16 [C,R] --------------------------
__global__ __launch_bounds__(256) void k_tr_bf(
    const __bf16* __restrict__ in, __bf16* __restrict__ out, int R, int C)
{
    __shared__ __bf16 t[64][65];
    int r0 = blockIdx.y * 64, c0 = blockIdx.x * 64;
#pragma unroll
    for (int i = 0; i < 16; ++i) {
        int e = i * 256 + threadIdx.x;
        int r = e >> 6, c = e & 63;
        t[c][r] = in[(size_t)(r0 + r) * C + c0 + c];
    }
    __syncthreads();
#pragma unroll
    for (int i = 0; i < 16; ++i) {
        int e = i * 256 + threadIdx.x;
        int r = e >> 6, c = e & 63;
        out[(size_t)(c0 + r) * R + r0 + c] = t[r][c];
    }
}

// ---------------- per-row argmax over S segments + histogram ------------------
__global__ __launch_bounds__(256) void k_argmax(
    const float* __restrict__ S0, int* __restrict__ idx_g, int* __restrict__ idx_l,
    int* __restrict__ cnt_g, int* __restrict__ cnt_l)
{
    __shared__ float sv[256];
    __shared__ int si[256];
    const int r = blockIdx.x, t = threadIdx.x;
    const float* row = S0 + (size_t)r * NCOMB;

    float best = -3.0e38f; int bi = 0;
    for (int c = t; c < NGLOB; c += 256) {
        float v = row[c];
        if (v > best) { best = v; bi = c; }   // ascending c: keeps first max
    }
    sv[t] = best; si[t] = bi;
    __syncthreads();
    for (int s = 128; s > 0; s >>= 1) {
        if (t < s) {
            if (sv[t + s] > sv[t] || (sv[t + s] == sv[t] && si[t + s] < si[t])) {
                sv[t] = sv[t + s]; si[t] = si[t + s];
            }
        }
        __syncthreads();
    }
    if (t == 0) { idx_g[r] = si[0]; atomicAdd(&cnt_g[si[0]], 1); }
    __syncthreads();

    float v = row[NGLOB + t];
    sv[t] = v; si[t] = t;
    __syncthreads();
    for (int s = 128; s > 0; s >>= 1) {
        if (t < s) {
            if (sv[t + s] > sv[t] || (sv[t + s] == sv[t] && si[t + s] < si[t])) {
                sv[t] = sv[t + s]; si[t] = si[t + s];
            }
        }
        __syncthreads();
    }
    if (t == 0) { idx_l[r] = si[0]; atomicAdd(&cnt_l[si[0]], 1); }
}

// ---------------- tiny serial exclusive scan ----------------------------------
__global__ void k_scan(const int* __restrict__ cg, const int* __restrict__ cl,
                       int* __restrict__ bg, int* __restrict__ bl)
{
    if (threadIdx.x == 0 && blockIdx.x == 0) {
        int s = 0;
        for (int i = 0; i < NGLOB; ++i) { bg[i] = s; s += cg[i]; }
        s = 0;
        for (int i = 0; i < NLOC; ++i) { bl[i] = s; s += cl[i]; }
    }
}

// ---------------- scatter row ids into per-code lists -------------------------
__global__ __launch_bounds__(256) void k_scatter(
    const int* __restrict__ idx_g, const int* __restrict__ idx_l,
    const int* __restrict__ base_g, const int* __restrict__ base_l,
    int* __restrict__ cur_g, int* __restrict__ cur_l,
    int* __restrict__ rl_g, int* __restrict__ rl_l)
{
    int n = blockIdx.x * 256 + threadIdx.x;
    int ig = idx_g[n];
    int p = atomicAdd(&cur_g[ig], 1);
    rl_g[base_g[ig] + p] = n;
    int il = idx_l[n];
    p = atomicAdd(&cur_l[il], 1);
    rl_l[base_l[il] + p] = n;
}

// ---------------- EMA dict update + l2norm -> bf16 comb_new -------------------
__global__ __launch_bounds__(256) void k_dict_update(
    const float* __restrict__ nn, const float* __restrict__ gdict, const float* __restrict__ ldict,
    const int* __restrict__ cnt_g, const int* __restrict__ cnt_l,
    const int* __restrict__ base_g, const int* __restrict__ base_l,
    const int* __restrict__ rl_g, const int* __restrict__ rl_l,
    __bf16* __restrict__ comb)
{
    __shared__ float sbuf[4];
    const int k = blockIdx.x, t = threadIdx.x;
    const float* drow;
    const int* list;
    int cnt; float m;
    if (k < NGLOB) { drow = gdict + (size_t)k * DIM; cnt = cnt_g[k]; list = rl_g + base_g[k]; m = MOM_G; }
    else { int kl = k - NGLOB; drow = ldict + (size_t)kl * DIM; cnt = cnt_l[kl]; list = rl_l + base_l[kl]; m = MOM_L; }
    const int d0 = t * 4;
    float a0 = 0, a1 = 0, a2 = 0, a3 = 0;
    for (int i = 0; i < cnt; ++i) {
        const float* rp = nn + (size_t)list[i] * DIM + d0;
        a0 += rp[0]; a1 += rp[1]; a2 += rp[2]; a3 += rp[3];
    }
    float u0 = drow[d0], u1 = drow[d0 + 1], u2 = drow[d0 + 2], u3 = drow[d0 + 3];
    if (cnt > 0) {
        float ic = (1.0f - m) / (float)cnt;
        u0 = m * u0 + a0 * ic; u1 = m * u1 + a1 * ic;
        u2 = m * u2 + a2 * ic; u3 = m * u3 + a3 * ic;
    }
    float ss = block_sum(u0 * u0 + u1 * u1 + u2 * u2 + u3 * u3, sbuf);
    float inv = 1.0f / fmaxf(sqrtf(ss), EPSN);
    bf16x4 o = {(__bf16)(u0 * inv), (__bf16)(u1 * inv), (__bf16)(u2 * inv), (__bf16)(u3 * inv)};
    *(bf16x4*)(comb + (size_t)k * DIM + d0) = o;
}

// ------- softmax over NCOMB + abs-sum losses; writes bf16 weights IN-PLACE ----
// weights row r stored as bf16 at (bf16*)(S + r*NCOMB), length NCOMB (half of
// the fp32 row's bytes -> no cross-row clobber; reads complete before writes).
__global__ __launch_bounds__(256) void k_softmax_loss(float* __restrict__ S, float* __restrict__ accum)
{
    __shared__ float sbuf[4];
    const int r = blockIdx.x, t = threadIdx.x;
    float* row = S + (size_t)r * NCOMB;
    __bf16* wrow = (__bf16*)row;
    float v[5];
    float mx = -3.0e38f, ag = 0.0f, al = 0.0f;
#pragma unroll
    for (int j = 0; j < 5; ++j) {
        v[j] = row[t + j * 256];
        mx = fmaxf(mx, v[j]);
        float a = fabsf(v[j]);
        if (j < 4) ag += a; else al += a;
    }
    mx = block_max(mx, sbuf);
    ag = block_sum(ag, sbuf);
    al = block_sum(al, sbuf);
    float e[5], es = 0.0f;
#pragma unroll
    for (int j = 0; j < 5; ++j) { e[j] = __expf((v[j] - mx) * TEMP_INV); es += e[j]; }
    es = block_sum(es, sbuf);
    float inv = 1.0f / es;
#pragma unroll
    for (int j = 0; j < 5; ++j) wrow[t + j * 256] = (__bf16)(e[j] * inv);
    if (t == 0) { atomicAdd(&accum[0], ag); atomicAdd(&accum[1], al); }
}

// ---------------- |row dot| for loss_direct (zn bf16, un fp32) ----------------
__global__ __launch_bounds__(256) void k_loss_direct(
    const __bf16* __restrict__ zn, const float* __restrict__ un, float* __restrict__ accum)
{
    __shared__ float sbuf[4];
    const int r = blockIdx.x, t = threadIdx.x;
    const __bf16* a = zn + (size_t)r * DIM + t * 4;
    const float* b = un + (size_t)r * DIM + t * 4;
    float d = (float)a[0] * b[0] + (float)a[1] * b[1] + (float)a[2] * b[2] + (float)a[3] * b[3];
    d = block_sum(d, sbuf);
    if (t == 0) atomicAdd(&accum[2], fabsf(d));
}

__global__ void k_loss_final(const float* __restrict__ accum, float* __restrict__ out_loss)
{
    if (threadIdx.x == 0 && blockIdx.x == 0)
        out_loss[0] = accum[0] / ((float)NROWS * (float)NGLOB)
                    + accum[1] / ((float)NROWS * (float)NLOC)
                    + accum[2] / (float)NROWS;
}

// ------------------------------------------------------------------------------
extern "C" void kernel_launch(void* const* d_in, const int* in_sizes, int n_in,
                              void* d_out, int out_size, void* d_ws, size_t ws_size,
                              hipStream_t stream)
{
    (void)in_sizes; (void)n_in; (void)out_size; (void)ws_size;
    const float* z_flat = (const float*)d_in[0];
    const float* u_flat = (const float*)d_in[1];
    const float* W1 = (const float*)d_in[2];
    const float* b1 = (const float*)d_in[3];
    const float* W2 = (const float*)d_in[4];
    const float* b2 = (const float*)d_in[5];
    const float* Wg = (const float*)d_in[6];
    const float* bg = (const float*)d_in[7];
    const float* gdict = (const float*)d_in[8];
    const float* ldict = (const float*)d_in[9];

    const size_t ND = (size_t)NROWS * DIM;
    const size_t NS = (size_t)NROWS * NCOMB;
    float* out = (float*)d_out;
    float* out_zclean = out;            // [N,D]
    float* out_loss = out + ND;         // scalar
    float* out_zproj = out + ND + 1;    // [N,D]  (4B-only-aligned base)
    float* out_u = out + 2 * ND + 1;    // [N,D]  (4B-only-aligned base)

    // ---- workspace layout (all 16B-aligned; total ~445 MB) ----
    char* w = (char*)d_ws;
    float* S = (float*)w;                         w += NS * 4;              // 168 MB (scores -> bf16 weights in-place)
    float* nn_gate = (float*)w;                   w += ND * 4;              // 134 MB (noise_norm fp32 -> gate fp32)
    __bf16* bufA = (__bf16*)w;                    w += ND * 2;              // 67 MB (z_bf16 -> zproj_bf16)
    __bf16* bufB = (__bf16*)w;                    w += ND * 2;              // 67 MB (u_bf16 -> h_bf16 -> znorm_bf16)
    __bf16* comb_old = (__bf16*)w;                w += (size_t)NCOMB * DIM * 2;
    __bf16* comb_new = (__bf16*)w;                w += (size_t)NCOMB * DIM * 2;
    __bf16* comb_newT = (__bf16*)w;               w += (size_t)NCOMB * DIM * 2;
    __bf16* W1T = (__bf16*)w;                     w += (size_t)DIM * DIM * 2;
    __bf16* W2T = (__bf16*)w;                     w += (size_t)DIM * DIM * 2;
    __bf16* WgT = (__bf16*)w;                     w += (size_t)DIM * DIM * 2;
    int* cnt_g = (int*)w;                         // contiguous int/ctrl region:
    int* cnt_l = cnt_g + NGLOB;
    int* cur_g = cnt_l + NLOC;
    int* cur_l = cur_g + NGLOB;
    float* accum = (float*)(cur_l + NLOC);        // 4 floats
    int* base_g = (int*)(accum + 4);
    int* base_l = base_g + NGLOB;
    int* idx_g = base_l + NLOC;
    int* idx_l = idx_g + NROWS;
    int* rl_g = idx_l + NROWS;
    int* rl_l = rl_g + NROWS;

    size_t zero_bytes = (size_t)(NGLOB + NLOC + NGLOB + NLOC + 4) * sizeof(int);
    hipMemsetAsync(cnt_g, 0, zero_bytes, stream);

    dim3 blk(256);

    // prep: conversions / transposes
    k_f2b<<<dim3(ND / 4 / 256), blk, 0, stream>>>(z_flat, bufA);               // z_bf16
    k_copy2<<<dim3(NCOMB * DIM / 256), blk, 0, stream>>>(gdict, ldict, comb_old);
    k_rownorm<<<dim3(NROWS), blk, 0, stream>>>(u_flat, nn_gate, bufB, out_u);  // nn fp32 + u_bf16 + copy
    k_tr_f2b<<<dim3(16, 16), blk, 0, stream>>>(W1, W1T, DIM);
    k_tr_f2b<<<dim3(16, 16), blk, 0, stream>>>(W2, W2T, DIM);
    k_tr_f2b<<<dim3(16, 16), blk, 0, stream>>>(Wg, WgT, DIM);

    // S0 = u_norm @ comb_old^T
    k_mgemm<0><<<dim3(NCOMB / 128, NROWS / 128), blk, 0, stream>>>(
        bufB, comb_old, NROWS, NCOMB, DIM, DIM, S, nullptr, nullptr, nullptr, nullptr);

    k_argmax<<<dim3(NROWS), blk, 0, stream>>>(S, idx_g, idx_l, cnt_g, cnt_l);
    k_scan<<<dim3(1), dim3(64), 0, stream>>>(cnt_g, cnt_l, base_g, base_l);
    k_scatter<<<dim3(NROWS / 256), blk, 0, stream>>>(idx_g, idx_l, base_g, base_l,
                                                     cur_g, cur_l, rl_g, rl_l);
    k_dict_update<<<dim3(NCOMB), blk, 0, stream>>>(nn_gate, gdict, ldict,
                                                   cnt_g, cnt_l, base_g, base_l,
                                                   rl_g, rl_l, comb_new);
    k_tr_bf<<<dim3(DIM / 64, NCOMB / 64), blk, 0, stream>>>(comb_new, comb_newT, NCOMB, DIM);

    // h = relu(z@W1+b1) -> bf16 bufB (u_bf16 dead)
    k_mgemm<1><<<dim3(DIM / 128, NROWS / 128), blk, 0, stream>>>(
        bufA, W1T, NROWS, DIM, DIM, DIM, nullptr, bufB, b1, nullptr, nullptr);
    // z_proj = h@W2+b2 -> fp32 out_zproj + bf16 bufA (z_bf16 dead)
    k_mgemm<2><<<dim3(DIM / 128, NROWS / 128), blk, 0, stream>>>(
        bufB, W2T, NROWS, DIM, DIM, DIM, out_zproj, bufA, b2, nullptr, nullptr);

    // z_norm -> bf16 bufB (h dead)
    k_rownorm<<<dim3(NROWS), blk, 0, stream>>>(out_zproj, nullptr, bufB, nullptr);
    k_loss_direct<<<dim3(NROWS), blk, 0, stream>>>(bufB, nn_gate, accum);

    // S1 = z_norm @ comb_new^T
    k_mgemm<0><<<dim3(NCOMB / 128, NROWS / 128), blk, 0, stream>>>(
        bufB, comb_new, NROWS, NCOMB, DIM, DIM, S, nullptr, nullptr, nullptr, nullptr);

    k_softmax_loss<<<dim3(NROWS), blk, 0, stream>>>(S, accum);   // -> bf16 weights in S

    // gate = sigmoid(z_proj@Wg+bg) -> fp32 nn_gate (noise_norm dead)
    k_mgemm<3><<<dim3(DIM / 128, NROWS / 128), blk, 0, stream>>>(
        bufA, WgT, NROWS, DIM, DIM, DIM, nn_gate, nullptr, bg, nullptr, nullptr);

    // z_clean = z - gate * (weights @ comb_new)   (A = bf16 weights, lda = 2*NCOMB)
    k_mgemm<4><<<dim3(DIM / 128, NROWS / 128), blk, 0, stream>>>(
        (const __bf16*)S, comb_newT, NROWS, DIM, NCOMB, 2 * NCOMB,
        out_zclean, nullptr, nullptr, z_flat, nn_gate);

    k_loss_final<<<dim3(1), dim3(64), 0, stream>>>(accum, out_loss);
}